// Round 9
// baseline (101.607 us; speedup 1.0000x reference)
//
#include <hip/hip_runtime.h>
#include <math.h>

#define EPSI 1e-8f
#define TOLI 1e-6f

typedef __fp16 half2v __attribute__((ext_vector_type(2)));

__device__ __forceinline__ float frcp(float x) { return __builtin_amdgcn_rcpf(x); }

// Key-only compare-exchange: unsigned min/max (2 VALU ops after unroll).
#define CE(A, B) {                                  \
    unsigned ka = key[A], kb = key[B];              \
    key[A] = ka < kb ? ka : kb;                     \
    key[B] = ka < kb ? kb : ka; }

// 256-thread WG (4 waves). Occupancy levers: f16-packed LDS stash -> 24KB/WG;
// __launch_bounds__(256,5) caps VGPR at 102 -> 5 WG/CU = 20 waves/CU
// (R6 was 12 at 48KB LDS). Kernel is issue-bound (R2: VALUBusy 60% ~ 3-4k
// wave-insts), so waves/CU is the lever; per-lane ILP (R8) regressed.
__global__ __launch_bounds__(256, 5) void diou3d_main(
    const float* __restrict__ pred, const float* __restrict__ tgt,
    float* __restrict__ partial, int n)
{
    __shared__ unsigned vbuf[24][256];  // f16x2-packed centered coords
    __shared__ float wsum[4];
    int tx = threadIdx.x;
    int tid = blockIdx.x * 256 + tx;
    float loss = 0.0f;
    if (tid < n) {
        const float* P = pred + (size_t)tid * 7;
        const float* T = tgt  + (size_t)tid * 7;
        float p0 = P[0], p1 = P[1], p2 = P[2], p3 = P[3], p4 = P[4], p5 = P[5], p6 = P[6];
        float t0 = T[0], t1 = T[1], t2 = T[2], t3 = T[3], t4 = T[4], t5 = T[5], t6 = T[6];

        // ---- 2D corners (cols 0,1,3,4,6) ----
        float sp, cp, st, ct;
        __sincosf(p6, &sp, &cp);
        __sincosf(t6, &st, &ct);
        const float hx[4] = {0.5f, -0.5f, -0.5f, 0.5f};
        const float hy[4] = {0.5f, 0.5f, -0.5f, -0.5f};
        float c1x[4], c1y[4], c2x[4], c2y[4];
#pragma unroll
        for (int k = 0; k < 4; k++) {
            float xa = hx[k] * p3, ya = hy[k] * p4;
            c1x[k] = xa * cp - ya * sp + p0;
            c1y[k] = xa * sp + ya * cp + p1;
            float xb = hx[k] * t3, yb = hy[k] * t4;
            c2x[k] = xb * ct - yb * st + t0;
            c2y[k] = xb * st + yb * ct + t1;
        }

        float vx[24], vy[24];
        float ma[24];   // mask as float (0/1): centroid = fma, 1 cndmask/vertex

        // ---- box_in_box: c1 corners in box2 (verts 0..3) ----
        {
            float abx = c2x[1] - c2x[0], aby = c2y[1] - c2y[0];
            float adx = c2x[3] - c2x[0], ady = c2y[3] - c2y[0];
            float rab = frcp(abx * abx + aby * aby);
            float rad = frcp(adx * adx + ady * ady);
#pragma unroll
            for (int k = 0; k < 4; k++) {
                float amx = c1x[k] - c2x[0], amy = c1y[k] - c2y[0];
                float pab = (abx * amx + aby * amy) * rab;
                float pad = (adx * amx + ady * amy) * rad;
                bool m = (pab > -TOLI) && (pab < 1.0f + TOLI) && (pad > -TOLI) && (pad < 1.0f + TOLI);
                ma[k] = m ? 1.0f : 0.0f;
                vx[k] = c1x[k]; vy[k] = c1y[k];
            }
        }
        // ---- box_in_box: c2 corners in box1 (verts 4..7) ----
        {
            float abx = c1x[1] - c1x[0], aby = c1y[1] - c1y[0];
            float adx = c1x[3] - c1x[0], ady = c1y[3] - c1y[0];
            float rab = frcp(abx * abx + aby * aby);
            float rad = frcp(adx * adx + ady * ady);
#pragma unroll
            for (int k = 0; k < 4; k++) {
                float amx = c2x[k] - c1x[0], amy = c2y[k] - c1y[0];
                float pab = (abx * amx + aby * amy) * rab;
                float pad = (adx * amx + ady * amy) * rad;
                bool m = (pab > -TOLI) && (pab < 1.0f + TOLI) && (pad > -TOLI) && (pad < 1.0f + TOLI);
                ma[4 + k] = m ? 1.0f : 0.0f;
                vx[4 + k] = c2x[k]; vy[4 + k] = c2y[k];
            }
        }

        // ---- edge-edge intersections (verts 8..23), sign-product masks ----
        //   t>0 <=> den_t*num>0 ; t<1 <=> (num-den_t)*num>0
        //   u>0 <=> den_u*num<0 ; u<1 <=> (num+den_u)*num>0   (u = -den_u/num)
        //   num==0 -> all products 0 -> false (matches reference t=u=-1)
#pragma unroll
        for (int i = 0; i < 4; i++) {
            float x1 = c1x[i], y1 = c1y[i];
            float dx12 = c1x[(i + 1) & 3] - x1, dy12 = c1y[(i + 1) & 3] - y1;
#pragma unroll
            for (int j = 0; j < 4; j++) {
                float x3 = c2x[j], y3 = c2y[j];
                float dx34 = c2x[(j + 1) & 3] - x3, dy34 = c2y[(j + 1) & 3] - y3;
                float num  = dy34 * dx12 - dx34 * dy12;
                float dxs = x1 - x3, dys = y1 - y3;
                float den_t = dx34 * dys - dy34 * dxs;
                float den_u = dx12 * dys - dy12 * dxs;
                bool m = (den_t * num > 0.0f) && ((num - den_t) * num > 0.0f)
                      && (den_u * num < 0.0f) && ((num + den_u) * num > 0.0f);
                float t2d = den_t * frcp(num + EPSI);  // reference's EPS-shifted parameter
                int idx = 8 + i * 4 + j;
                vx[idx] = x1 + t2d * dx12;
                vy[idx] = y1 + t2d * dy12;
                ma[idx] = m ? 1.0f : 0.0f;
            }
        }

        // ---- centroid over valid vertices (fma form) ----
        float cntf = 0.0f, sx = 0.0f, sy = 0.0f;
#pragma unroll
        for (int k = 0; k < 24; k++) {
            cntf += ma[k];
            sx = fmaf(ma[k], vx[k], sx);
            sy = fmaf(ma[k], vy[k], sy);
        }
        int ic = (int)cntf;
        float rnv = frcp(fmaxf(cntf, 1.0f));
        float mx = sx * rnv, my = sy * rnv;

        // ---- center, stash f16-packed to LDS, build sortable uint key ----
        // key = monotone(uint(pseudoangle)) with low 5 bits = vertex index
        // (stable tie-break == reference stable argsort; invalid = 0xFFFFFFE0|k)
        unsigned key[24];
#pragma unroll
        for (int k = 0; k < 24; k++) {
            float ux = vx[k] - mx, uy = vy[k] - my;
            half2v h = __builtin_amdgcn_cvt_pkrtz(ux, uy);
            vbuf[k][tx] = __builtin_bit_cast(unsigned, h);
            float d = fabsf(ux) + fabsf(uy);
            float pq = ux * frcp(d);
            pq = (d == 0.0f) ? 0.0f : pq;
            float ang = (uy < 0.0f) ? (pq - 1.0f) : (1.0f - pq);
            unsigned u = __float_as_uint(ang);
            u ^= (unsigned)(((int)u >> 31)) | 0x80000000u;   // sortable uint
            unsigned kk = (u & 0xFFFFFFE0u) | (unsigned)k;
            key[k] = (ma[k] != 0.0f) ? kk : (0xFFFFFFE0u | (unsigned)k);
        }

        // ---- Batcher odd-even mergesort, n=32, comparators hitting idx>=24
        //      skipped (ascending CEs + virtual +inf padding never move) ----
#pragma unroll
        for (int p = 1; p < 32; p <<= 1) {
#pragma unroll
            for (int k = p; k >= 1; k >>= 1) {
#pragma unroll
                for (int j = k & (p - 1); j + k < 32; j += 2 * k) {
#pragma unroll
                    for (int i = 0; i < k; i++) {
                        int lo = i + j, hi = i + j + k;
                        if (hi < 24 && (lo / (2 * p) == hi / (2 * p))) {
                            CE(lo, hi);
                        }
                    }
                }
            }
        }

        // ---- gather first 12 sorted vertices from LDS (lane-private column;
        //      per-lane program order, no barrier; bank = tx%32, conflict-free) ----
        float gx[12], gy[12];
#pragma unroll
        for (int s = 0; s < 12; s++) {
            int idx = (int)(key[s] & 31u);
            half2v h = __builtin_bit_cast(half2v, vbuf[idx][tx]);
            gx[s] = (float)h.x; gy[s] = (float)h.y;
        }

        // ---- pad invalid slots with sorted-first, shoelace over 12 ----
        float x0 = gx[0], y0 = gy[0];
#pragma unroll
        for (int s = 0; s < 12; s++) {
            bool v = (s < ic);
            gx[s] = v ? gx[s] : x0;
            gy[s] = v ? gy[s] : y0;
        }
        float area2 = 0.0f;
#pragma unroll
        for (int s = 0; s < 12; s++) {
            int ns = (s == 11) ? 0 : s + 1;
            area2 += gx[s] * gy[ns] - gy[s] * gx[ns];
        }
        float inter2d = 0.5f * fabsf(area2);

        // ---- z-overlap, volumes, IoU ----
        float zmax1 = p2 + 0.5f * p5, zmin1 = p2 - 0.5f * p5;
        float zmax2 = t2 + 0.5f * t5, zmin2 = t2 - 0.5f * t5;
        float zov = fmaxf(fminf(zmax1, zmax2) - fmaxf(zmin1, zmin2), 0.0f);
        float inter3d = inter2d * zov;
        float vol1 = p3 * p4 * p5, vol2 = t3 * t4 * t5;
        float iou = inter3d / (vol1 + vol2 - inter3d);
        if (isnan(iou)) iou = 0.0f;   // jnp.nan_to_num(..., nan=0.0)

        // ---- center distance ----
        float d0 = p0 - t0, d1 = p1 - t1, d2 = p2 - t2;
        float ctd = d0 * d0 + d1 * d1 + d2 * d2;

        // ---- corner distance, closed form (verified rounds 2..8) ----
        float cosd = cp * ct + sp * st;   // cos(theta_p - theta_t)
        float dp2 = p3 * p3 + p4 * p4 + p5 * p5;
        float dt2 = t3 * t3 + t4 * t4 + t5 * t5;   // == did
        float crossd = p3 * t3 * cosd + p4 * t4 + p5 * t5 * cosd;
        float cnd = ctd + 0.25f * (dp2 + dt2) - 0.5f * crossd;

        float dterm = (ctd + cnd) / (ctd + cnd + dt2 + 1e-6f);
        loss = 1.0f - iou + dterm;
    }

    // ---- wave reduction, then cross-wave via LDS ----
#pragma unroll
    for (int off = 32; off > 0; off >>= 1) loss += __shfl_down(loss, off);
    int lane = tx & 63, wid = tx >> 6;
    if (lane == 0) wsum[wid] = loss;
    __syncthreads();
    if (tx == 0)
        partial[blockIdx.x] = wsum[0] + wsum[1] + wsum[2] + wsum[3];
}

__global__ __launch_bounds__(256) void diou3d_reduce(
    const float* __restrict__ partial, int nblocks, float* __restrict__ out, float invn)
{
    float s = 0.0f;
    for (int i = threadIdx.x; i < nblocks; i += 256) s += partial[i];
#pragma unroll
    for (int off = 32; off > 0; off >>= 1) s += __shfl_down(s, off);
    __shared__ float wsum[4];
    int lane = threadIdx.x & 63, wid = threadIdx.x >> 6;
    if (lane == 0) wsum[wid] = s;
    __syncthreads();
    if (threadIdx.x == 0)
        out[0] = (wsum[0] + wsum[1] + wsum[2] + wsum[3]) * invn;
}

extern "C" void kernel_launch(void* const* d_in, const int* in_sizes, int n_in,
                              void* d_out, int out_size, void* d_ws, size_t ws_size,
                              hipStream_t stream) {
    const float* pred = (const float*)d_in[0];
    const float* tgt  = (const float*)d_in[1];
    float* out = (float*)d_out;
    int n = in_sizes[0] / 7;
    const int T = 256;
    int blocks = (n + T - 1) / T;
    float* partial = (float*)d_ws;   // fully written each call (poison-safe)
    diou3d_main<<<blocks, T, 0, stream>>>(pred, tgt, partial, n);
    diou3d_reduce<<<1, 256, 0, stream>>>(partial, blocks, out, 1.0f / (float)n);
}

// Round 10
// 78.669 us; speedup vs baseline: 1.2916x; 1.2916x over previous
//
#include <hip/hip_runtime.h>
#include <math.h>

#define EPSI 1e-8f
#define TOLI 1e-6f

typedef __fp16 half2v __attribute__((ext_vector_type(2)));

__device__ __forceinline__ float frcp(float x) { return __builtin_amdgcn_rcpf(x); }

// Key-only compare-exchange: unsigned min/max (2 VALU ops after unroll).
#define CE(A, B) {                                  \
    unsigned ka = key[A], kb = key[B];              \
    key[A] = ka < kb ? ka : kb;                     \
    key[B] = ka < kb ? kb : ka; }

// 256-thread WG (4 waves), f16-packed LDS stash -> 24KB/WG.
// __launch_bounds__(256,4): 128-VGPR cap. (256,5) = 102-cap caused wholesale
// scratch spills (R9: VGPR 48, 110MB scratch traffic, main 44.5us) — the
// allocator needs ~80-100 VGPR for the vertex arrays.
__global__ __launch_bounds__(256, 4) void diou3d_main(
    const float* __restrict__ pred, const float* __restrict__ tgt,
    float* __restrict__ partial, int n)
{
    __shared__ unsigned vbuf[24][256];  // f16x2-packed centered coords
    __shared__ float wsum[4];
    int tx = threadIdx.x;
    int tid = blockIdx.x * 256 + tx;
    float loss = 0.0f;
    if (tid < n) {
        const float* P = pred + (size_t)tid * 7;
        const float* T = tgt  + (size_t)tid * 7;
        float p0 = P[0], p1 = P[1], p2 = P[2], p3 = P[3], p4 = P[4], p5 = P[5], p6 = P[6];
        float t0 = T[0], t1 = T[1], t2 = T[2], t3 = T[3], t4 = T[4], t5 = T[5], t6 = T[6];

        // ---- 2D corners (cols 0,1,3,4,6) ----
        float sp, cp, st, ct;
        __sincosf(p6, &sp, &cp);
        __sincosf(t6, &st, &ct);
        const float hx[4] = {0.5f, -0.5f, -0.5f, 0.5f};
        const float hy[4] = {0.5f, 0.5f, -0.5f, -0.5f};
        float c1x[4], c1y[4], c2x[4], c2y[4];
#pragma unroll
        for (int k = 0; k < 4; k++) {
            float xa = hx[k] * p3, ya = hy[k] * p4;
            c1x[k] = xa * cp - ya * sp + p0;
            c1y[k] = xa * sp + ya * cp + p1;
            float xb = hx[k] * t3, yb = hy[k] * t4;
            c2x[k] = xb * ct - yb * st + t0;
            c2y[k] = xb * st + yb * ct + t1;
        }

        float vx[24], vy[24];
        float ma[24];   // mask as float (0/1): centroid = fma, 1 cndmask/vertex

        // ---- box_in_box: c1 corners in box2 (verts 0..3) ----
        {
            float abx = c2x[1] - c2x[0], aby = c2y[1] - c2y[0];
            float adx = c2x[3] - c2x[0], ady = c2y[3] - c2y[0];
            float rab = frcp(abx * abx + aby * aby);
            float rad = frcp(adx * adx + ady * ady);
#pragma unroll
            for (int k = 0; k < 4; k++) {
                float amx = c1x[k] - c2x[0], amy = c1y[k] - c2y[0];
                float pab = (abx * amx + aby * amy) * rab;
                float pad = (adx * amx + ady * amy) * rad;
                bool m = (pab > -TOLI) && (pab < 1.0f + TOLI) && (pad > -TOLI) && (pad < 1.0f + TOLI);
                ma[k] = m ? 1.0f : 0.0f;
                vx[k] = c1x[k]; vy[k] = c1y[k];
            }
        }
        // ---- box_in_box: c2 corners in box1 (verts 4..7) ----
        {
            float abx = c1x[1] - c1x[0], aby = c1y[1] - c1y[0];
            float adx = c1x[3] - c1x[0], ady = c1y[3] - c1y[0];
            float rab = frcp(abx * abx + aby * aby);
            float rad = frcp(adx * adx + ady * ady);
#pragma unroll
            for (int k = 0; k < 4; k++) {
                float amx = c2x[k] - c1x[0], amy = c2y[k] - c1y[0];
                float pab = (abx * amx + aby * amy) * rab;
                float pad = (adx * amx + ady * amy) * rad;
                bool m = (pab > -TOLI) && (pab < 1.0f + TOLI) && (pad > -TOLI) && (pad < 1.0f + TOLI);
                ma[4 + k] = m ? 1.0f : 0.0f;
                vx[4 + k] = c2x[k]; vy[4 + k] = c2y[k];
            }
        }

        // ---- edge-edge intersections (verts 8..23), sign-product masks ----
        //   t>0 <=> den_t*num>0 ; t<1 <=> (num-den_t)*num>0
        //   u>0 <=> den_u*num<0 ; u<1 <=> (num+den_u)*num>0   (u = -den_u/num)
        //   num==0 -> all products 0 -> false (matches reference t=u=-1)
#pragma unroll
        for (int i = 0; i < 4; i++) {
            float x1 = c1x[i], y1 = c1y[i];
            float dx12 = c1x[(i + 1) & 3] - x1, dy12 = c1y[(i + 1) & 3] - y1;
#pragma unroll
            for (int j = 0; j < 4; j++) {
                float x3 = c2x[j], y3 = c2y[j];
                float dx34 = c2x[(j + 1) & 3] - x3, dy34 = c2y[(j + 1) & 3] - y3;
                float num  = dy34 * dx12 - dx34 * dy12;
                float dxs = x1 - x3, dys = y1 - y3;
                float den_t = dx34 * dys - dy34 * dxs;
                float den_u = dx12 * dys - dy12 * dxs;
                bool m = (den_t * num > 0.0f) && ((num - den_t) * num > 0.0f)
                      && (den_u * num < 0.0f) && ((num + den_u) * num > 0.0f);
                float t2d = den_t * frcp(num + EPSI);  // reference's EPS-shifted parameter
                int idx = 8 + i * 4 + j;
                vx[idx] = x1 + t2d * dx12;
                vy[idx] = y1 + t2d * dy12;
                ma[idx] = m ? 1.0f : 0.0f;
            }
        }

        // ---- centroid over valid vertices (fma form) ----
        float cntf = 0.0f, sx = 0.0f, sy = 0.0f;
#pragma unroll
        for (int k = 0; k < 24; k++) {
            cntf += ma[k];
            sx = fmaf(ma[k], vx[k], sx);
            sy = fmaf(ma[k], vy[k], sy);
        }
        int ic = (int)cntf;
        float rnv = frcp(fmaxf(cntf, 1.0f));
        float mx = sx * rnv, my = sy * rnv;

        // ---- center, stash f16-packed to LDS, build sortable uint key ----
        // key = monotone(uint(pseudoangle)) with low 5 bits = vertex index
        // (stable tie-break == reference stable argsort; invalid = 0xFFFFFFE0|k)
        unsigned key[24];
#pragma unroll
        for (int k = 0; k < 24; k++) {
            float ux = vx[k] - mx, uy = vy[k] - my;
            half2v h = __builtin_amdgcn_cvt_pkrtz(ux, uy);
            vbuf[k][tx] = __builtin_bit_cast(unsigned, h);
            float d = fabsf(ux) + fabsf(uy);
            float pq = ux * frcp(d);
            pq = (d == 0.0f) ? 0.0f : pq;
            float ang = (uy < 0.0f) ? (pq - 1.0f) : (1.0f - pq);
            unsigned u = __float_as_uint(ang);
            u ^= (unsigned)(((int)u >> 31)) | 0x80000000u;   // sortable uint
            unsigned kk = (u & 0xFFFFFFE0u) | (unsigned)k;
            key[k] = (ma[k] != 0.0f) ? kk : (0xFFFFFFE0u | (unsigned)k);
        }

        // ---- Batcher odd-even mergesort, n=32, comparators hitting idx>=24
        //      skipped (ascending CEs + virtual +inf padding never move) ----
#pragma unroll
        for (int p = 1; p < 32; p <<= 1) {
#pragma unroll
            for (int k = p; k >= 1; k >>= 1) {
#pragma unroll
                for (int j = k & (p - 1); j + k < 32; j += 2 * k) {
#pragma unroll
                    for (int i = 0; i < k; i++) {
                        int lo = i + j, hi = i + j + k;
                        if (hi < 24 && (lo / (2 * p) == hi / (2 * p))) {
                            CE(lo, hi);
                        }
                    }
                }
            }
        }

        // ---- gather first 12 sorted vertices from LDS (lane-private column;
        //      per-lane program order, no barrier; bank = tx%32, conflict-free) ----
        float gx[12], gy[12];
#pragma unroll
        for (int s = 0; s < 12; s++) {
            int idx = (int)(key[s] & 31u);
            half2v h = __builtin_bit_cast(half2v, vbuf[idx][tx]);
            gx[s] = (float)h.x; gy[s] = (float)h.y;
        }

        // ---- pad invalid slots with sorted-first, shoelace over 12 ----
        float x0 = gx[0], y0 = gy[0];
#pragma unroll
        for (int s = 0; s < 12; s++) {
            bool v = (s < ic);
            gx[s] = v ? gx[s] : x0;
            gy[s] = v ? gy[s] : y0;
        }
        float area2 = 0.0f;
#pragma unroll
        for (int s = 0; s < 12; s++) {
            int ns = (s == 11) ? 0 : s + 1;
            area2 += gx[s] * gy[ns] - gy[s] * gx[ns];
        }
        float inter2d = 0.5f * fabsf(area2);

        // ---- z-overlap, volumes, IoU ----
        float zmax1 = p2 + 0.5f * p5, zmin1 = p2 - 0.5f * p5;
        float zmax2 = t2 + 0.5f * t5, zmin2 = t2 - 0.5f * t5;
        float zov = fmaxf(fminf(zmax1, zmax2) - fmaxf(zmin1, zmin2), 0.0f);
        float inter3d = inter2d * zov;
        float vol1 = p3 * p4 * p5, vol2 = t3 * t4 * t5;
        float iou = inter3d / (vol1 + vol2 - inter3d);
        if (isnan(iou)) iou = 0.0f;   // jnp.nan_to_num(..., nan=0.0)

        // ---- center distance ----
        float d0 = p0 - t0, d1 = p1 - t1, d2 = p2 - t2;
        float ctd = d0 * d0 + d1 * d1 + d2 * d2;

        // ---- corner distance, closed form (verified rounds 2..8) ----
        float cosd = cp * ct + sp * st;   // cos(theta_p - theta_t)
        float dp2 = p3 * p3 + p4 * p4 + p5 * p5;
        float dt2 = t3 * t3 + t4 * t4 + t5 * t5;   // == did
        float crossd = p3 * t3 * cosd + p4 * t4 + p5 * t5 * cosd;
        float cnd = ctd + 0.25f * (dp2 + dt2) - 0.5f * crossd;

        float dterm = (ctd + cnd) / (ctd + cnd + dt2 + 1e-6f);
        loss = 1.0f - iou + dterm;
    }

    // ---- wave reduction, then cross-wave via LDS ----
#pragma unroll
    for (int off = 32; off > 0; off >>= 1) loss += __shfl_down(loss, off);
    int lane = tx & 63, wid = tx >> 6;
    if (lane == 0) wsum[wid] = loss;
    __syncthreads();
    if (tx == 0)
        partial[blockIdx.x] = wsum[0] + wsum[1] + wsum[2] + wsum[3];
}

__global__ __launch_bounds__(256) void diou3d_reduce(
    const float* __restrict__ partial, int nblocks, float* __restrict__ out, float invn)
{
    float s = 0.0f;
    for (int i = threadIdx.x; i < nblocks; i += 256) s += partial[i];
#pragma unroll
    for (int off = 32; off > 0; off >>= 1) s += __shfl_down(s, off);
    __shared__ float wsum[4];
    int lane = threadIdx.x & 63, wid = threadIdx.x >> 6;
    if (lane == 0) wsum[wid] = s;
    __syncthreads();
    if (threadIdx.x == 0)
        out[0] = (wsum[0] + wsum[1] + wsum[2] + wsum[3]) * invn;
}

extern "C" void kernel_launch(void* const* d_in, const int* in_sizes, int n_in,
                              void* d_out, int out_size, void* d_ws, size_t ws_size,
                              hipStream_t stream) {
    const float* pred = (const float*)d_in[0];
    const float* tgt  = (const float*)d_in[1];
    float* out = (float*)d_out;
    int n = in_sizes[0] / 7;
    const int T = 256;
    int blocks = (n + T - 1) / T;
    float* partial = (float*)d_ws;   // fully written each call (poison-safe)
    diou3d_main<<<blocks, T, 0, stream>>>(pred, tgt, partial, n);
    diou3d_reduce<<<1, 256, 0, stream>>>(partial, blocks, out, 1.0f / (float)n);
}

// Round 11
// 75.161 us; speedup vs baseline: 1.3518x; 1.0467x over previous
//
#include <hip/hip_runtime.h>
#include <math.h>

#define EPSI 1e-8f

typedef __fp16 half2v __attribute__((ext_vector_type(2)));

__device__ __forceinline__ float frcp(float x) { return __builtin_amdgcn_rcpf(x); }

// Key-only compare-exchange: unsigned min/max (2 VALU ops after unroll).
#define CE(A, B) {                                  \
    unsigned ka = key[A], kb = key[B];              \
    key[A] = ka < kb ? ka : kb;                     \
    key[B] = ka < kb ? kb : ka; }

// 256-thread WG (4 waves), f16-packed LDS stash -> 24KB/WG, (256,4)=128-VGPR
// cap (102-cap spilled wholesale in R9). R10 showed occupancy lever exhausted;
// this round deletes instructions instead: rectangle edge structure
// (d_{i+2} = -d_i) factors the 16 intersections to 4 rcps + half-cross
// differences, and corner-in-box == sign(den_t) over the same quantities.
__global__ __launch_bounds__(256, 4) void diou3d_main(
    const float* __restrict__ pred, const float* __restrict__ tgt,
    float* __restrict__ partial, int n)
{
    __shared__ unsigned vbuf[24][256];  // f16x2-packed centered coords
    __shared__ float wsum[4];
    int tx = threadIdx.x;
    int tid = blockIdx.x * 256 + tx;
    float loss = 0.0f;
    if (tid < n) {
        const float* P = pred + (size_t)tid * 7;
        const float* T = tgt  + (size_t)tid * 7;
        float p0 = P[0], p1 = P[1], p2 = P[2], p3 = P[3], p4 = P[4], p5 = P[5], p6 = P[6];
        float t0 = T[0], t1 = T[1], t2 = T[2], t3 = T[3], t4 = T[4], t5 = T[5], t6 = T[6];

        // ---- 2D corners (cols 0,1,3,4,6), CCW ----
        float sp, cp, st, ct;
        __sincosf(p6, &sp, &cp);
        __sincosf(t6, &st, &ct);
        const float hx[4] = {0.5f, -0.5f, -0.5f, 0.5f};
        const float hy[4] = {0.5f, 0.5f, -0.5f, -0.5f};
        float c1x[4], c1y[4], c2x[4], c2y[4];
#pragma unroll
        for (int k = 0; k < 4; k++) {
            float xa = hx[k] * p3, ya = hy[k] * p4;
            c1x[k] = xa * cp - ya * sp + p0;
            c1y[k] = xa * sp + ya * cp + p1;
            float xb = hx[k] * t3, yb = hy[k] * t4;
            c2x[k] = xb * ct - yb * st + t0;
            c2y[k] = xb * st + yb * ct + t1;
        }

        float vx[24], vy[24];
        float ma[24];   // mask as float (0/1)

        // corner slots 0..7
#pragma unroll
        for (int k = 0; k < 4; k++) {
            vx[k] = c1x[k];     vy[k] = c1y[k];
            vx[4 + k] = c2x[k]; vy[4 + k] = c2y[k];
        }

        // ---- factored intersections + in-box tests ----
        // Rectangle: edge i dir = s_i * e1[i&1], s_i = (i<2 ? +1 : -1); same for box2.
        // num[i][j]   = s_i*s_j*bnum[i&1][j&1]           (4 distinct crosses, 4 rcps)
        // den_t[i][j] = s_j*(A[j&1][i] - Bv[j])  = s_j*g
        // den_u[i][j] = s_i*(Dv[i] - C[i&1][j])  = -s_i*h,  h = C - Dv
        // t = den_t/(num+-EPS) = s_i * g*rb ; u = -den_u/num = s_j * h*rb
        // point = p_i + t*d1_i = p_i + (g*rb)*e1[i&1]     (signs cancel)
        // c1_i in box2  <=> den_t[i][j]>=0 all j <=> g[i][0..1]>=0 & g[i][2..3]<=0
        // c2_j in box1  <=> den_u[i][j]<=0 all i <=> h[0..1][j]>=0 & h[2..3][j]<=0
        float e1x[2], e1y[2], e2x[2], e2y[2];
        e1x[0] = c1x[1] - c1x[0]; e1y[0] = c1y[1] - c1y[0];
        e1x[1] = c1x[2] - c1x[1]; e1y[1] = c1y[2] - c1y[1];
        e2x[0] = c2x[1] - c2x[0]; e2y[0] = c2y[1] - c2y[0];
        e2x[1] = c2x[2] - c2x[1]; e2y[1] = c2y[2] - c2y[1];

        float rb[2][2];
#pragma unroll
        for (int a = 0; a < 2; a++)
#pragma unroll
            for (int b = 0; b < 2; b++) {
                float bn = e2y[b] * e1x[a] - e2x[b] * e1y[a];
                rb[a][b] = frcp(bn + EPSI);
            }

        float A_[2][4], Bv[4], C_[2][4], Dv[4];
#pragma unroll
        for (int b = 0; b < 2; b++)
#pragma unroll
            for (int i = 0; i < 4; i++)
                A_[b][i] = e2x[b] * c1y[i] - e2y[b] * c1x[i];
#pragma unroll
        for (int j = 0; j < 4; j++)
            Bv[j] = e2x[j & 1] * c2y[j] - e2y[j & 1] * c2x[j];
#pragma unroll
        for (int a = 0; a < 2; a++)
#pragma unroll
            for (int j = 0; j < 4; j++)
                C_[a][j] = e1x[a] * c2y[j] - e1y[a] * c2x[j];
#pragma unroll
        for (int i = 0; i < 4; i++)
            Dv[i] = e1x[i & 1] * c1y[i] - e1y[i & 1] * c1x[i];

        float hmn[4], hmx[4];
#pragma unroll
        for (int i = 0; i < 4; i++) {
            float gmn = 0.0f, gmx = 0.0f;
#pragma unroll
            for (int j = 0; j < 4; j++) {
                const int a = i & 1, b = j & 1;
                float g = A_[b][i] - Bv[j];
                float h = C_[a][j] - Dv[i];
                float r = rb[a][b];
                float tau = g * r;
                float ups = h * r;
                bool mt = (i < 2) ? (tau > 0.0f && tau < 1.0f)
                                  : (tau > -1.0f && tau < 0.0f);
                bool mu = (j < 2) ? (ups > 0.0f && ups < 1.0f)
                                  : (ups > -1.0f && ups < 0.0f);
                const int idx = 8 + i * 4 + j;
                vx[idx] = fmaf(tau, e1x[a], c1x[i]);
                vy[idx] = fmaf(tau, e1y[a], c1y[i]);
                ma[idx] = (mt && mu) ? 1.0f : 0.0f;
                if (j == 0) gmn = g; else if (j == 1) gmn = fminf(gmn, g);
                else if (j == 2) gmx = g; else gmx = fmaxf(gmx, g);
                if (i == 0) hmn[j] = h;
                else if (i == 1) hmn[j] = fminf(hmn[j], h);
                else if (i == 2) hmx[j] = h;
                else hmx[j] = fmaxf(hmx[j], h);
            }
            ma[i] = (gmn >= 0.0f && gmx <= 0.0f) ? 1.0f : 0.0f;
        }
#pragma unroll
        for (int j = 0; j < 4; j++)
            ma[4 + j] = (hmn[j] >= 0.0f && hmx[j] <= 0.0f) ? 1.0f : 0.0f;

        // ---- centroid over valid vertices (fma form) ----
        float cntf = 0.0f, sx = 0.0f, sy = 0.0f;
#pragma unroll
        for (int k = 0; k < 24; k++) {
            cntf += ma[k];
            sx = fmaf(ma[k], vx[k], sx);
            sy = fmaf(ma[k], vy[k], sy);
        }
        int ic = (int)cntf;
        float rnv = frcp(fmaxf(cntf, 1.0f));
        float mx = sx * rnv, my = sy * rnv;

        // ---- center, stash f16-packed to LDS, build sortable uint key ----
        // key = monotone(uint(pseudoangle)) with low 5 bits = vertex index
        // (stable tie-break == reference stable argsort; invalid = 0xFFFFFFE0|k)
        unsigned key[24];
#pragma unroll
        for (int k = 0; k < 24; k++) {
            float ux = vx[k] - mx, uy = vy[k] - my;
            half2v h = __builtin_amdgcn_cvt_pkrtz(ux, uy);
            vbuf[k][tx] = __builtin_bit_cast(unsigned, h);
            float d = fabsf(ux) + fabsf(uy);
            float pq = ux * frcp(d);
            pq = (d == 0.0f) ? 0.0f : pq;
            float ang = (uy < 0.0f) ? (pq - 1.0f) : (1.0f - pq);
            unsigned u = __float_as_uint(ang);
            u ^= (unsigned)(((int)u >> 31)) | 0x80000000u;   // sortable uint
            unsigned kk = (u & 0xFFFFFFE0u) | (unsigned)k;
            key[k] = (ma[k] != 0.0f) ? kk : (0xFFFFFFE0u | (unsigned)k);
        }

        // ---- Batcher odd-even mergesort, n=32, comparators hitting idx>=24
        //      skipped (ascending CEs + virtual +inf padding never move) ----
#pragma unroll
        for (int p = 1; p < 32; p <<= 1) {
#pragma unroll
            for (int k = p; k >= 1; k >>= 1) {
#pragma unroll
                for (int j = k & (p - 1); j + k < 32; j += 2 * k) {
#pragma unroll
                    for (int i = 0; i < k; i++) {
                        int lo = i + j, hi = i + j + k;
                        if (hi < 24 && (lo / (2 * p) == hi / (2 * p))) {
                            CE(lo, hi);
                        }
                    }
                }
            }
        }

        // ---- gather first 12 sorted vertices from LDS (lane-private column;
        //      per-lane program order, no barrier; bank = tx%32, conflict-free) ----
        float gx[12], gy[12];
#pragma unroll
        for (int s = 0; s < 12; s++) {
            int idx = (int)(key[s] & 31u);
            half2v h = __builtin_bit_cast(half2v, vbuf[idx][tx]);
            gx[s] = (float)h.x; gy[s] = (float)h.y;
        }

        // ---- pad invalid slots with sorted-first, shoelace over 12 ----
        float x0 = gx[0], y0 = gy[0];
#pragma unroll
        for (int s = 0; s < 12; s++) {
            bool v = (s < ic);
            gx[s] = v ? gx[s] : x0;
            gy[s] = v ? gy[s] : y0;
        }
        float area2 = 0.0f;
#pragma unroll
        for (int s = 0; s < 12; s++) {
            int ns = (s == 11) ? 0 : s + 1;
            area2 += gx[s] * gy[ns] - gy[s] * gx[ns];
        }
        float inter2d = 0.5f * fabsf(area2);

        // ---- z-overlap, volumes, IoU ----
        float zmax1 = p2 + 0.5f * p5, zmin1 = p2 - 0.5f * p5;
        float zmax2 = t2 + 0.5f * t5, zmin2 = t2 - 0.5f * t5;
        float zov = fmaxf(fminf(zmax1, zmax2) - fmaxf(zmin1, zmin2), 0.0f);
        float inter3d = inter2d * zov;
        float vol1 = p3 * p4 * p5, vol2 = t3 * t4 * t5;
        float iou = inter3d / (vol1 + vol2 - inter3d);
        if (isnan(iou)) iou = 0.0f;   // jnp.nan_to_num(..., nan=0.0)

        // ---- center distance ----
        float d0 = p0 - t0, d1 = p1 - t1, d2 = p2 - t2;
        float ctd = d0 * d0 + d1 * d1 + d2 * d2;

        // ---- corner distance, closed form (verified rounds 2..10) ----
        float cosd = cp * ct + sp * st;   // cos(theta_p - theta_t)
        float dp2 = p3 * p3 + p4 * p4 + p5 * p5;
        float dt2 = t3 * t3 + t4 * t4 + t5 * t5;   // == did
        float crossd = p3 * t3 * cosd + p4 * t4 + p5 * t5 * cosd;
        float cnd = ctd + 0.25f * (dp2 + dt2) - 0.5f * crossd;

        float dterm = (ctd + cnd) / (ctd + cnd + dt2 + 1e-6f);
        loss = 1.0f - iou + dterm;
    }

    // ---- wave reduction, then cross-wave via LDS ----
#pragma unroll
    for (int off = 32; off > 0; off >>= 1) loss += __shfl_down(loss, off);
    int lane = tx & 63, wid = tx >> 6;
    if (lane == 0) wsum[wid] = loss;
    __syncthreads();
    if (tx == 0)
        partial[blockIdx.x] = wsum[0] + wsum[1] + wsum[2] + wsum[3];
}

__global__ __launch_bounds__(256) void diou3d_reduce(
    const float* __restrict__ partial, int nblocks, float* __restrict__ out, float invn)
{
    float s = 0.0f;
    for (int i = threadIdx.x; i < nblocks; i += 256) s += partial[i];
#pragma unroll
    for (int off = 32; off > 0; off >>= 1) s += __shfl_down(s, off);
    __shared__ float wsum[4];
    int lane = threadIdx.x & 63, wid = threadIdx.x >> 6;
    if (lane == 0) wsum[wid] = s;
    __syncthreads();
    if (threadIdx.x == 0)
        out[0] = (wsum[0] + wsum[1] + wsum[2] + wsum[3]) * invn;
}

extern "C" void kernel_launch(void* const* d_in, const int* in_sizes, int n_in,
                              void* d_out, int out_size, void* d_ws, size_t ws_size,
                              hipStream_t stream) {
    const float* pred = (const float*)d_in[0];
    const float* tgt  = (const float*)d_in[1];
    float* out = (float*)d_out;
    int n = in_sizes[0] / 7;
    const int T = 256;
    int blocks = (n + T - 1) / T;
    float* partial = (float*)d_ws;   // fully written each call (poison-safe)
    diou3d_main<<<blocks, T, 0, stream>>>(pred, tgt, partial, n);
    diou3d_reduce<<<1, 256, 0, stream>>>(partial, blocks, out, 1.0f / (float)n);
}